// Round 4
// baseline (579.790 us; speedup 1.0000x reference)
//
#include <hip/hip_runtime.h>

#define DH 128   // D_IN == D_H == 128
#define TR 64    // rows per tile
#define NT 8     // tiles per block

typedef __attribute__((ext_vector_type(8))) short bf16x8;
typedef __attribute__((ext_vector_type(8))) unsigned short u16x8;
typedef __attribute__((ext_vector_type(4))) float f32x4;
typedef __attribute__((ext_vector_type(4))) int   i32x4;

__device__ inline unsigned rnd_bf16(float f){
  unsigned u = __builtin_bit_cast(unsigned, f);
  u += 0x7fffu + ((u >> 16) & 1u);   // RNE
  return u;
}
__device__ inline int pk2(float a, float b){
  unsigned ua = rnd_bf16(a), ub = rnd_bf16(b);
  return (int)((ua >> 16) | (ub & 0xffff0000u));
}
__device__ inline float fsigmoid(float v){
  float e = __builtin_amdgcn_exp2f(v * -1.442695040888963f);
  return __builtin_amdgcn_rcpf(1.0f + e);
}
__device__ inline float ftanhf(float v){
  float e = __builtin_amdgcn_exp2f(v * 2.885390081777927f); // e^{2v}
  return 1.0f - 2.0f * __builtin_amdgcn_rcpf(1.0f + e);
}

// Wf[wid 8][ks 8][g 4][lane 64] 16B fragments: lane (l15,lg) holds
// col = wid*16+l15 of gate g, k = ks*32+lg*8 .. +8 (k<128: W_x*, else W_h*).
__global__ void prep_weights(const float* __restrict__ Wxi, const float* __restrict__ Whi, const float* __restrict__ bi,
                             const float* __restrict__ Wxf, const float* __restrict__ Whf, const float* __restrict__ bf_,
                             const float* __restrict__ Wxc, const float* __restrict__ Whc, const float* __restrict__ bc,
                             const float* __restrict__ Wxo, const float* __restrict__ Who, const float* __restrict__ bo,
                             u16x8* __restrict__ Wf, float* __restrict__ bcat){
  int gid  = blockIdx.x * 256 + threadIdx.x;   // 0..16383
  int lane = gid & 63;
  int g    = (gid >> 6) & 3;
  int ks   = (gid >> 8) & 7;
  int wd   = (gid >> 11) & 7;
  int l15 = lane & 15, lg = lane >> 4;
  int hcol = wd * 16 + l15;
  int kb   = ks * 32 + lg * 8;
  const float* Wx = (g == 0) ? Wxi : (g == 1) ? Wxf : (g == 2) ? Wxc : Wxo;
  const float* Wh = (g == 0) ? Whi : (g == 1) ? Whf : (g == 2) ? Whc : Who;
  u16x8 o;
  #pragma unroll
  for (int j = 0; j < 8; ++j){
    int k = kb + j;
    float v = (k < 128) ? Wx[k * DH + hcol] : Wh[(k - 128) * DH + hcol];
    o[j] = (unsigned short)(rnd_bf16(v) >> 16);
  }
  Wf[gid] = o;
  if (gid < 512){
    int gg = gid >> 7, hc = gid & 127;
    const float* bp = (gg == 0) ? bi : (gg == 1) ? bf_ : (gg == 2) ? bc : bo;
    bcat[gid] = bp[hc];
  }
}

// Persistent pipelined LSTM. 512 thr = 8 waves; wave w owns gate-cols
// [w*16, w*16+16) of all 4 gates for ALL 64 rows of the tile (acc[4][4]).
// LDS: xh[2][64 rows][32 slots of 16B] bf16, slot swizzle s^(row&7).
__global__ __launch_bounds__(512, 4)
void lstm_fused(const float* __restrict__ x, const float* __restrict__ hin,
                const float* __restrict__ cin, const bf16x8* __restrict__ Wf,
                const float* __restrict__ bcat, float* __restrict__ out, int Btot){
  __shared__ __attribute__((aligned(16))) bf16x8 xh[2][TR * 32];

  const int tid = threadIdx.x;
  const int l   = tid & 63;
  const int wid = tid >> 6;        // 0..7
  const int l15 = l & 15;
  const int lg  = l >> 4;          // 0..3
  const int col = wid * 16 + l15;  // h-col this lane owns

  const float bb0 = bcat[          col];
  const float bb1 = bcat[128 +     col];
  const float bb2 = bcat[256 +     col];
  const float bb3 = bcat[384 +     col];

  const bf16x8* wv = Wf + (size_t)wid * 2048 + l;  // [ks][g] stride 64

  // staging map: thread covers (row = i*32 + tid>>4, k8 = tid&15) for i=0,1
  const int srow = tid >> 4;       // 0..31
  const int sc8  = tid & 15;       // 16B-slot within x (or h) half

  const size_t o1 = (size_t)Btot * DH;
  size_t tile = (size_t)blockIdx.x * NT;

  // ---- prologue: stage tile 0 into buf 0
  {
    const float* xb = x   + tile * TR * DH;
    const float* hb = hin + tile * TR * DH;
    #pragma unroll
    for (int i = 0; i < 2; ++i){
      int row = i * 32 + srow;
      const float* px = xb + row * DH + sc8 * 8;
      const float* ph = hb + row * DH + sc8 * 8;
      float4 a0 = *(const float4*)px, a1 = *(const float4*)(px + 4);
      float4 b0 = *(const float4*)ph, b1 = *(const float4*)(ph + 4);
      i32x4 p;
      p[0] = pk2(a0.x, a0.y); p[1] = pk2(a0.z, a0.w);
      p[2] = pk2(a1.x, a1.y); p[3] = pk2(a1.z, a1.w);
      xh[0][row * 32 + ( sc8       ^ (row & 7))] = __builtin_bit_cast(bf16x8, p);
      p[0] = pk2(b0.x, b0.y); p[1] = pk2(b0.z, b0.w);
      p[2] = pk2(b1.x, b1.y); p[3] = pk2(b1.z, b1.w);
      xh[0][row * 32 + ((16 + sc8) ^ (row & 7))] = __builtin_bit_cast(bf16x8, p);
    }
  }
  __syncthreads();

  for (int it = 0; it < NT; ++it, ++tile){
    const int cb = it & 1, nb = cb ^ 1;
    const size_t rowb = tile * TR;
    const bool pf = (it + 1 < NT);
    const float* nxb = x   + (rowb + TR) * DH;
    const float* nhb = hin + (rowb + TR) * DH;

    // issue next-tile x loads (hidden under ks 0..3)
    float4 sx[4];
    if (pf){
      #pragma unroll
      for (int i = 0; i < 2; ++i){
        const float* px = nxb + (i * 32 + srow) * DH + sc8 * 8;
        sx[i * 2]     = *(const float4*)px;
        sx[i * 2 + 1] = *(const float4*)(px + 4);
      }
    }

    f32x4 acc[4][4];
    #pragma unroll
    for (int m = 0; m < 4; ++m)
      #pragma unroll
      for (int g = 0; g < 4; ++g)
        acc[m][g] = (f32x4){0.f, 0.f, 0.f, 0.f};

    // ---- ks 0..3 : x half (slots 0..15)
    #pragma unroll
    for (int ks = 0; ks < 4; ++ks){
      bf16x8 a[4];
      #pragma unroll
      for (int m = 0; m < 4; ++m){
        int row = m * 16 + l15;
        a[m] = xh[cb][row * 32 + ((ks * 4 + lg) ^ (row & 7))];
      }
      #pragma unroll
      for (int g = 0; g < 4; ++g){
        bf16x8 bw = wv[(ks * 4 + g) * 64];
        #pragma unroll
        for (int m = 0; m < 4; ++m)
          acc[m][g] = __builtin_amdgcn_mfma_f32_16x16x32_bf16(a[m], bw, acc[m][g], 0, 0, 0);
      }
    }

    // write next-tile x to other buf; issue next-tile h loads
    float4 sh[4];
    if (pf){
      #pragma unroll
      for (int i = 0; i < 2; ++i){
        int row = i * 32 + srow;
        i32x4 p;
        p[0] = pk2(sx[i*2].x, sx[i*2].y); p[1] = pk2(sx[i*2].z, sx[i*2].w);
        p[2] = pk2(sx[i*2+1].x, sx[i*2+1].y); p[3] = pk2(sx[i*2+1].z, sx[i*2+1].w);
        xh[nb][row * 32 + (sc8 ^ (row & 7))] = __builtin_bit_cast(bf16x8, p);
        const float* ph = nhb + row * DH + sc8 * 8;
        sh[i * 2]     = *(const float4*)ph;
        sh[i * 2 + 1] = *(const float4*)(ph + 4);
      }
    }

    // ---- ks 4..7 : h half (slots 16..31)
    #pragma unroll
    for (int ks = 4; ks < 8; ++ks){
      bf16x8 a[4];
      #pragma unroll
      for (int m = 0; m < 4; ++m){
        int row = m * 16 + l15;
        a[m] = xh[cb][row * 32 + ((ks * 4 + lg) ^ (row & 7))];
      }
      #pragma unroll
      for (int g = 0; g < 4; ++g){
        bf16x8 bw = wv[(ks * 4 + g) * 64];
        #pragma unroll
        for (int m = 0; m < 4; ++m)
          acc[m][g] = __builtin_amdgcn_mfma_f32_16x16x32_bf16(a[m], bw, acc[m][g], 0, 0, 0);
      }
    }

    // write next-tile h
    if (pf){
      #pragma unroll
      for (int i = 0; i < 2; ++i){
        int row = i * 32 + srow;
        i32x4 p;
        p[0] = pk2(sh[i*2].x, sh[i*2].y); p[1] = pk2(sh[i*2].z, sh[i*2].w);
        p[2] = pk2(sh[i*2+1].x, sh[i*2+1].y); p[3] = pk2(sh[i*2+1].z, sh[i*2+1].w);
        xh[nb][row * 32 + ((16 + sc8) ^ (row & 7))] = __builtin_bit_cast(bf16x8, p);
      }
    }
    __syncthreads();   // next iter may now read nb; epilogue overlaps others' k-loop

    // ---- epilogue tile it (lane-local gates)
    #pragma unroll
    for (int m = 0; m < 4; ++m){
      #pragma unroll
      for (int r = 0; r < 4; ++r){
        const size_t idx = (rowb + m * 16 + lg * 4 + r) * DH + col;
        float gi = acc[m][0][r] + bb0;
        float gf = acc[m][1][r] + bb1;
        float gc = acc[m][2][r] + bb2;
        float go = acc[m][3][r] + bb3;
        float i_t = fsigmoid(gi);
        float f_t = fsigmoid(gf);
        float g_t = ftanhf(gc);
        float o_t = fsigmoid(go);
        float cn = f_t * cin[idx] + i_t * g_t;
        float hn = o_t * ftanhf(cn);
        out[idx]          = hn;
        out[o1 + idx]     = hn;
        out[2 * o1 + idx] = cn;
      }
    }
  }
}

extern "C" void kernel_launch(void* const* d_in, const int* in_sizes, int n_in,
                              void* d_out, int out_size, void* d_ws, size_t ws_size,
                              hipStream_t stream){
  const float* x  = (const float*)d_in[0];
  const float* ht = (const float*)d_in[1];
  const float* ct = (const float*)d_in[2];
  u16x8* Wf   = (u16x8*)d_ws;                        // 16384 * 16B = 256KB
  float* bcat = (float*)((char*)d_ws + 16384 * 16);  // +2KB
  const int Btot = in_sizes[0] / DH;

  prep_weights<<<64, 256, 0, stream>>>(
      (const float*)d_in[3],  (const float*)d_in[4],  (const float*)d_in[5],
      (const float*)d_in[6],  (const float*)d_in[7],  (const float*)d_in[8],
      (const float*)d_in[9],  (const float*)d_in[10], (const float*)d_in[11],
      (const float*)d_in[12], (const float*)d_in[13], (const float*)d_in[14],
      Wf, bcat);

  const int nblocks = Btot / (TR * NT);   // 512 for B=262144
  lstm_fused<<<nblocks, 512, 0, stream>>>(x, ht, ct, (const bf16x8*)Wf, bcat,
                                          (float*)d_out, Btot);
}